// Round 13
// baseline (97.762 us; speedup 1.0000x reference)
//
#include <hip/hip_runtime.h>
#include <math.h>

#define B 128
#define E 6
#define IN_DIM 1664
#define H_DIM 512
#define OUT_DIM 618
#define ZD 32
#define K2 544
#define S1 13             // L1 split-K (KPB=4)
#define S23 9             // L2/L3 split-K (8x2kb + 1 z-split)

typedef __attribute__((ext_vector_type(8))) short short8;
typedef __attribute__((ext_vector_type(4))) float f32x4;
union U128 { uint4 u4; short8 s8; ushort us[8]; };

__device__ __forceinline__ ushort f2bf(float f) {   // fp32 -> bf16 RNE
    uint u = __float_as_uint(f);
    u += 0x7fffu + ((u >> 16) & 1u);
    return (ushort)(u >> 16);
}
__device__ __forceinline__ float elu1(float x) { return x < 0.f ? expm1f(x) : x; }

// MFMA frag math (HW-validated r3-r12):
//  A frag (kb,m): lane l -> row 16m+(l&15), k = 32kb+(l>>4)*8+j
//  B frag (kb,nf): lane l -> col 16nf+(l&15), k = 32kb+(l>>4)*8+j
//  C/D: col = l&15, row = (l>>4)*4 + r

// ---------------------------------------------------------------------------
// init_bias: y1,y2,out <- coef-blended biases. Gemms atomically accumulate
// on top (fence-free; device-scope atomics). Consumers apply elu inline.
// ---------------------------------------------------------------------------
__global__ __launch_bounds__(256) void init_bias(
    const float* __restrict__ coef,
    const float* __restrict__ b1, const float* __restrict__ b2,
    const float* __restrict__ b3,
    float* __restrict__ y1, float* __restrict__ y2, float* __restrict__ out)
{
    const int idx = blockIdx.x * 256 + threadIdx.x;
    if (idx >= B * (2 * H_DIM + OUT_DIM)) return;
    const int b = idx / (2 * H_DIM + OUT_DIM);
    const int o = idx - b * (2 * H_DIM + OUT_DIM);
    float ce[E];
    #pragma unroll
    for (int e = 0; e < E; ++e) ce[e] = coef[b * E + e];
    float v = 0.f;
    if (o < H_DIM) {
        #pragma unroll
        for (int e = 0; e < E; ++e) v = fmaf(ce[e], b1[e * H_DIM + o], v);
        y1[b * H_DIM + o] = v;
    } else if (o < 2 * H_DIM) {
        const int oo = o - H_DIM;
        #pragma unroll
        for (int e = 0; e < E; ++e) v = fmaf(ce[e], b2[e * H_DIM + oo], v);
        y2[b * H_DIM + oo] = v;
    } else {
        const int oo = o - 2 * H_DIM;
        #pragma unroll
        for (int e = 0; e < E; ++e) v = fmaf(ce[e], b3[e * OUT_DIM + oo], v);
        out[b * OUT_DIM + oo] = v;
    }
}

// ---------------------------------------------------------------------------
// gemm1: L1, block tile 128x32, KPB=4 (24 steps), grid 16x13. ZERO LDS, ZERO
// barriers: each wave gathers its own B-frags from global (strided scalar
// loads, 2-step ring — no barrier means the ring actually stays in flight).
// A-frags from fp32 x*coef in-register. Epilogue: atomicAdd into y1.
// ---------------------------------------------------------------------------
__global__ __launch_bounds__(256) void gemm1(
    const float* __restrict__ x,     // [B][IN_DIM]
    const float* __restrict__ coef,  // [B][E]
    const float* __restrict__ w,     // [E][IN_DIM][H_DIM]
    float* __restrict__ y1)          // [B][H_DIM] accum
{
    constexpr int NS = E * 4;        // 24 steps
    const int tid = threadIdx.x;
    const int l = tid & 63, wv = tid >> 6;
    const int n0 = blockIdx.x * 32, kb0 = blockIdx.y * 4;
    const int row0 = 32 * wv + (l & 15), row1 = row0 + 16, kq = l >> 4;
    const int colf = n0 + (l & 15);          // frag-0 column for this lane

    float ce0[E], ce1[E];
    #pragma unroll
    for (int e = 0; e < E; ++e) {
        ce0[e] = coef[row0 * E + e];
        ce1[e] = coef[row1 * E + e];
    }

    // B gather: frag element j = W[e][32kb + kq*8 + j][colf (+16)]
    auto ld_Bfrag = [&](int s, float (*r)[8]) {
        const int e = s % E, kb = kb0 + s / E;
        const float* base = w + ((size_t)e * IN_DIM + kb * 32 + kq * 8) * H_DIM + colf;
        #pragma unroll
        for (int j = 0; j < 8; ++j) {
            r[0][j] = base[(size_t)j * H_DIM];
            r[1][j] = base[(size_t)j * H_DIM + 16];
        }
    };
    auto ld_X = [&](int kb, float4* xr) {
        const float* p0 = x + (size_t)row0 * IN_DIM + kb * 32 + kq * 8;
        const float* p1 = x + (size_t)row1 * IN_DIM + kb * 32 + kq * 8;
        xr[0] = *reinterpret_cast<const float4*>(p0);
        xr[1] = *reinterpret_cast<const float4*>(p0 + 4);
        xr[2] = *reinterpret_cast<const float4*>(p1);
        xr[3] = *reinterpret_cast<const float4*>(p1 + 4);
    };

    f32x4 acc00 = {0.f,0.f,0.f,0.f}, acc01 = {0.f,0.f,0.f,0.f};
    f32x4 acc10 = {0.f,0.f,0.f,0.f}, acc11 = {0.f,0.f,0.f,0.f};

    float br[2][2][8];               // 2-step ring x 2 frags x 8
    float4 xreg[2][4];
    ld_Bfrag(0, br[0]); ld_Bfrag(1, br[1]);
    ld_X(kb0, xreg[0]); ld_X(kb0 + 1, xreg[1]);

    #pragma unroll
    for (int s = 0; s < NS; ++s) {
        const int rs = s & 1, e = s % E, kbi = s / E;

        U128 b0, b1;
        #pragma unroll
        for (int j = 0; j < 8; ++j) {
            b0.us[j] = f2bf(br[rs][0][j]);
            b1.us[j] = f2bf(br[rs][1][j]);
        }

        const float4* xc = xreg[kbi & 1];
        U128 a0, a1;
        a0.us[0] = f2bf(xc[0].x * ce0[e]); a0.us[1] = f2bf(xc[0].y * ce0[e]);
        a0.us[2] = f2bf(xc[0].z * ce0[e]); a0.us[3] = f2bf(xc[0].w * ce0[e]);
        a0.us[4] = f2bf(xc[1].x * ce0[e]); a0.us[5] = f2bf(xc[1].y * ce0[e]);
        a0.us[6] = f2bf(xc[1].z * ce0[e]); a0.us[7] = f2bf(xc[1].w * ce0[e]);
        a1.us[0] = f2bf(xc[2].x * ce1[e]); a1.us[1] = f2bf(xc[2].y * ce1[e]);
        a1.us[2] = f2bf(xc[2].z * ce1[e]); a1.us[3] = f2bf(xc[2].w * ce1[e]);
        a1.us[4] = f2bf(xc[3].x * ce1[e]); a1.us[5] = f2bf(xc[3].y * ce1[e]);
        a1.us[6] = f2bf(xc[3].z * ce1[e]); a1.us[7] = f2bf(xc[3].w * ce1[e]);

        if (s + 2 < NS) ld_Bfrag(s + 2, br[rs]);            // ring refill
        if (e == E - 1 && kbi + 2 < 4)                      // x prefetch
            ld_X(kb0 + kbi + 2, xreg[kbi & 1]);

        acc00 = __builtin_amdgcn_mfma_f32_16x16x32_bf16(a0.s8, b0.s8, acc00, 0, 0, 0);
        acc01 = __builtin_amdgcn_mfma_f32_16x16x32_bf16(a0.s8, b1.s8, acc01, 0, 0, 0);
        acc10 = __builtin_amdgcn_mfma_f32_16x16x32_bf16(a1.s8, b0.s8, acc10, 0, 0, 0);
        acc11 = __builtin_amdgcn_mfma_f32_16x16x32_bf16(a1.s8, b1.s8, acc11, 0, 0, 0);
    }

    const int colB = n0 + (l & 15);
    const int rsub = (l >> 4) << 2;
    #pragma unroll
    for (int mi = 0; mi < 2; ++mi) {
        const int row = wv * 32 + mi * 16 + rsub;
        const f32x4 c0 = mi ? acc10 : acc00;
        const f32x4 c1 = mi ? acc11 : acc01;
        #pragma unroll
        for (int r = 0; r < 4; ++r) {
            atomicAdd(&y1[(size_t)(row + r) * H_DIM + colB],      c0[r]);
            atomicAdd(&y1[(size_t)(row + r) * H_DIM + colB + 16], c1[r]);
        }
    }
}

// ---------------------------------------------------------------------------
// gemm_mid: L2/L3, barrier-free like gemm1. Prologue: O(1) loads (elu(yin)
// or raw z). Per-wave B gather with 2-step ring. Epilogue: atomicAdd.
// ---------------------------------------------------------------------------
template<int KPB, bool ZS, int NW, bool GUARD>
__device__ __forceinline__ void gemm_mid_body(
    const float* __restrict__ yin,   // [B][H_DIM] accum(+bias) pre-ELU
    const float* __restrict__ coef,  // [B][E]
    const float* __restrict__ z,     // [B][ZD]
    const float* __restrict__ w,     // [E][K2][NW]
    float* __restrict__ yout,        // [B][NW] accum (bias pre-init)
    int nt, int kb0)
{
    constexpr int NS = E * KPB;
    const int tid = threadIdx.x;
    const int l = tid & 63, wv = tid >> 6;
    const int n0 = nt * 32;
    const int row0 = 32 * wv + (l & 15), row1 = row0 + 16, kq = l >> 4;
    const int colf = n0 + (l & 15);
    const bool ok0 = !GUARD || colf < NW;
    const bool ok1 = !GUARD || colf + 16 < NW;

    float ce0[E], ce1[E];
    #pragma unroll
    for (int e = 0; e < E; ++e) {
        ce0[e] = coef[row0 * E + e];
        ce1[e] = coef[row1 * E + e];
    }

    // ---- prologue: per-thread activations for this k-range ----
    float v0[KPB * 8], v1[KPB * 8];
    if (ZS) {
        const float4 za = *reinterpret_cast<const float4*>(z + row0 * ZD + kq * 8);
        const float4 zb = *reinterpret_cast<const float4*>(z + row0 * ZD + kq * 8 + 4);
        const float4 zc = *reinterpret_cast<const float4*>(z + row1 * ZD + kq * 8);
        const float4 zd = *reinterpret_cast<const float4*>(z + row1 * ZD + kq * 8 + 4);
        v0[0]=za.x; v0[1]=za.y; v0[2]=za.z; v0[3]=za.w;
        v0[4]=zb.x; v0[5]=zb.y; v0[6]=zb.z; v0[7]=zb.w;
        v1[0]=zc.x; v1[1]=zc.y; v1[2]=zc.z; v1[3]=zc.w;
        v1[4]=zd.x; v1[5]=zd.y; v1[6]=zd.z; v1[7]=zd.w;
    } else {
        #pragma unroll
        for (int kbi = 0; kbi < KPB; ++kbi) {
            const int kk = (kb0 + kbi) * 32 + kq * 8;
            const float* p0 = yin + (size_t)row0 * H_DIM + kk;
            const float* p1 = yin + (size_t)row1 * H_DIM + kk;
            const float4 a = *reinterpret_cast<const float4*>(p0);
            const float4 b = *reinterpret_cast<const float4*>(p0 + 4);
            const float4 c = *reinterpret_cast<const float4*>(p1);
            const float4 d = *reinterpret_cast<const float4*>(p1 + 4);
            v0[kbi*8+0]=elu1(a.x); v0[kbi*8+1]=elu1(a.y);
            v0[kbi*8+2]=elu1(a.z); v0[kbi*8+3]=elu1(a.w);
            v0[kbi*8+4]=elu1(b.x); v0[kbi*8+5]=elu1(b.y);
            v0[kbi*8+6]=elu1(b.z); v0[kbi*8+7]=elu1(b.w);
            v1[kbi*8+0]=elu1(c.x); v1[kbi*8+1]=elu1(c.y);
            v1[kbi*8+2]=elu1(c.z); v1[kbi*8+3]=elu1(c.w);
            v1[kbi*8+4]=elu1(d.x); v1[kbi*8+5]=elu1(d.y);
            v1[kbi*8+6]=elu1(d.z); v1[kbi*8+7]=elu1(d.w);
        }
    }

    auto ld_Bfrag = [&](int s, float (*r)[8]) {
        const int e = s % E, kb = kb0 + s / E;
        const float* base = w + ((size_t)e * K2 + kb * 32 + kq * 8) * NW + colf;
        #pragma unroll
        for (int j = 0; j < 8; ++j) {
            r[0][j] = ok0 ? base[(size_t)j * NW] : 0.f;
            r[1][j] = ok1 ? base[(size_t)j * NW + 16] : 0.f;
        }
    };

    f32x4 acc00 = {0.f,0.f,0.f,0.f}, acc01 = {0.f,0.f,0.f,0.f};
    f32x4 acc10 = {0.f,0.f,0.f,0.f}, acc11 = {0.f,0.f,0.f,0.f};

    float br[2][2][8];
    ld_Bfrag(0, br[0]);
    if (NS > 1) ld_Bfrag(1, br[1]);

    #pragma unroll
    for (int s = 0; s < NS; ++s) {
        const int rs = s & 1, e = s % E, kbi = s / E;

        U128 b0, b1;
        #pragma unroll
        for (int j = 0; j < 8; ++j) {
            b0.us[j] = f2bf(br[rs][0][j]);
            b1.us[j] = f2bf(br[rs][1][j]);
        }

        U128 a0, a1;
        #pragma unroll
        for (int j = 0; j < 8; ++j) {
            a0.us[j] = f2bf(v0[kbi * 8 + j] * ce0[e]);
            a1.us[j] = f2bf(v1[kbi * 8 + j] * ce1[e]);
        }

        if (s + 2 < NS) ld_Bfrag(s + 2, br[rs]);

        acc00 = __builtin_amdgcn_mfma_f32_16x16x32_bf16(a0.s8, b0.s8, acc00, 0, 0, 0);
        acc01 = __builtin_amdgcn_mfma_f32_16x16x32_bf16(a0.s8, b1.s8, acc01, 0, 0, 0);
        acc10 = __builtin_amdgcn_mfma_f32_16x16x32_bf16(a1.s8, b0.s8, acc10, 0, 0, 0);
        acc11 = __builtin_amdgcn_mfma_f32_16x16x32_bf16(a1.s8, b1.s8, acc11, 0, 0, 0);
    }

    const int colB = n0 + (l & 15);
    const int rsub = (l >> 4) << 2;
    #pragma unroll
    for (int mi = 0; mi < 2; ++mi) {
        const int row = wv * 32 + mi * 16 + rsub;
        const f32x4 c0 = mi ? acc10 : acc00;
        const f32x4 c1 = mi ? acc11 : acc01;
        #pragma unroll
        for (int r = 0; r < 4; ++r) {
            if (ok0) atomicAdd(&yout[(size_t)(row + r) * NW + colB], c0[r]);
            if (ok1) atomicAdd(&yout[(size_t)(row + r) * NW + colB + 16], c1[r]);
        }
    }
}

__global__ __launch_bounds__(256) void gemm_l2(
    const float* __restrict__ y1, const float* __restrict__ coef,
    const float* __restrict__ z, const float* __restrict__ w2,
    float* __restrict__ y2)
{
    const int nt = blockIdx.x, sp = blockIdx.y;
    if (sp < 8)
        gemm_mid_body<2, false, H_DIM, false>(y1, coef, z, w2, y2, nt, sp * 2);
    else
        gemm_mid_body<1, true, H_DIM, false>(y1, coef, z, w2, y2, nt, 16);
}

__global__ __launch_bounds__(256) void gemm_l3(
    const float* __restrict__ y2, const float* __restrict__ coef,
    const float* __restrict__ z, const float* __restrict__ w3,
    float* __restrict__ out)
{
    const int nt = blockIdx.x, sp = blockIdx.y;
    if (sp < 8)
        gemm_mid_body<2, false, OUT_DIM, true>(y2, coef, z, w3, out, nt, sp * 2);
    else
        gemm_mid_body<1, true, OUT_DIM, true>(y2, coef, z, w3, out, nt, 16);
}

extern "C" void kernel_launch(void* const* d_in, const int* in_sizes, int n_in,
                              void* d_out, int out_size, void* d_ws, size_t ws_size,
                              hipStream_t stream)
{
    const float* p_prev = (const float*)d_in[0];
    const float* coef   = (const float*)d_in[1];
    const float* z      = (const float*)d_in[2];
    const float* w1     = (const float*)d_in[3];
    const float* b1     = (const float*)d_in[4];
    const float* w2     = (const float*)d_in[5];
    const float* b2     = (const float*)d_in[6];
    const float* w3     = (const float*)d_in[7];
    const float* b3     = (const float*)d_in[8];
    float* out = (float*)d_out;

    // ws: y1 | y2 (fp32 accumulators, re-initialized every call by init_bias)
    float* y1 = (float*)d_ws;            // [B][512]
    float* y2 = y1 + (size_t)B * H_DIM;  // [B][512]

    const int TOT = B * (2 * H_DIM + OUT_DIM);
    init_bias<<<(TOT + 255) / 256, 256, 0, stream>>>(coef, b1, b2, b3, y1, y2, out);
    gemm1<<<dim3(16, S1), 256, 0, stream>>>(p_prev, coef, w1, y1);
    gemm_l2<<<dim3(16, S23), 256, 0, stream>>>(y1, coef, z, w2, y2);
    gemm_l3<<<dim3(20, S23), 256, 0, stream>>>(y2, coef, z, w3, out);
}

// Round 14
// 45.288 us; speedup vs baseline: 2.1587x; 2.1587x over previous
//
#include <hip/hip_runtime.h>
#include <math.h>

#define B 128
#define E 6
#define IN_DIM 1664
#define H_DIM 512
#define OUT_DIM 618
#define ZD 32
#define K2 544
#define S1 26             // L1 split-K (KPB=2)
#define S23 17            // L2/L3 split-K (16x1kb + 1 z-split)

typedef __attribute__((ext_vector_type(8))) short short8;
typedef __attribute__((ext_vector_type(4))) float f32x4;
union U128 { uint4 u4; short8 s8; ushort us[8]; };

__device__ __forceinline__ ushort f2bf(float f) {   // fp32 -> bf16 RNE
    uint u = __float_as_uint(f);
    u += 0x7fffu + ((u >> 16) & 1u);
    return (ushort)(u >> 16);
}
__device__ __forceinline__ uint pk2(float a, float b) {
    return (uint)f2bf(a) | ((uint)f2bf(b) << 16);
}
__device__ __forceinline__ float elu1(float x) { return x < 0.f ? expm1f(x) : x; }

// MFMA frag math (HW-validated r3-r13):
//  A frag (kb,m): lane l -> row 16m+(l&15), k = 32kb+(l>>4)*8+j
//  B frag (kb,nf): lane l -> col 16nf+(l&15), k = 32kb+(l>>4)*8+j
//  C/D: col = l&15, row = (l>>4)*4 + r

// ---------------------------------------------------------------------------
// init_bias: y1,y2,out <- coef-blended biases. Gemms atomically accumulate
// on top (fence-free device-scope atomics); consumers apply elu inline.
// ---------------------------------------------------------------------------
__global__ __launch_bounds__(256) void init_bias(
    const float* __restrict__ coef,
    const float* __restrict__ b1, const float* __restrict__ b2,
    const float* __restrict__ b3,
    float* __restrict__ y1, float* __restrict__ y2, float* __restrict__ out)
{
    const int idx = blockIdx.x * 256 + threadIdx.x;
    if (idx >= B * (2 * H_DIM + OUT_DIM)) return;
    const int b = idx / (2 * H_DIM + OUT_DIM);
    const int o = idx - b * (2 * H_DIM + OUT_DIM);
    float ce[E];
    #pragma unroll
    for (int e = 0; e < E; ++e) ce[e] = coef[b * E + e];
    float v = 0.f;
    if (o < H_DIM) {
        #pragma unroll
        for (int e = 0; e < E; ++e) v = fmaf(ce[e], b1[e * H_DIM + o], v);
        y1[b * H_DIM + o] = v;
    } else if (o < 2 * H_DIM) {
        const int oo = o - H_DIM;
        #pragma unroll
        for (int e = 0; e < E; ++e) v = fmaf(ce[e], b2[e * H_DIM + oo], v);
        y2[b * H_DIM + oo] = v;
    } else {
        const int oo = o - 2 * H_DIM;
        #pragma unroll
        for (int e = 0; e < E; ++e) v = fmaf(ce[e], b3[e * OUT_DIM + oo], v);
        out[b * OUT_DIM + oo] = v;
    }
}

// ---------------------------------------------------------------------------
// gemm1: L1, block tile 128 rows x 16 cols, KPB=2 (12 steps), grid 32x26 =
// 832 blocks (~3.2/CU: barrier drains overlap across blocks). W fp32 tile
// (32k x 16n) staged per step: thread stages a k-pair as one packed 4B
// ds_write into frag layout (dbuf, 2-deep reg ring, 1 barrier/step).
// A-frags from fp32 x*coef in-register. Epilogue: atomicAdd into y1.
// ---------------------------------------------------------------------------
__global__ __launch_bounds__(256) void gemm1(
    const float* __restrict__ x,     // [B][IN_DIM]
    const float* __restrict__ coef,  // [B][E]
    const float* __restrict__ w,     // [E][IN_DIM][H_DIM]
    float* __restrict__ y1)          // [B][H_DIM] accum (bias pre-init)
{
    constexpr int NS = E * 2;        // 12 steps
    const int tid = threadIdx.x;
    const int l = tid & 63, wv = tid >> 6;
    const int n0 = blockIdx.x * 16, kb0 = blockIdx.y * 2;
    const int tn = tid & 15, tq = tid >> 4;          // staging: col tn, k-pair 2tq
    const int lp = ((tq >> 2) << 4) | tn;            // frag lane slot
    const int j0 = (2 * tq) & 7;                     // j offset (0/2/4/6)
    const int row0 = 32 * wv + (l & 15), row1 = row0 + 16, kq = l >> 4;

    __shared__ ushort bs[2][64][8];                  // dbuf x lane x j, 2KB

    float ce0[E], ce1[E];
    #pragma unroll
    for (int e = 0; e < E; ++e) {
        ce0[e] = coef[row0 * E + e];
        ce1[e] = coef[row1 * E + e];
    }

    auto ld_B = [&](int s, float* r) {
        const int e = s % E, kb = kb0 + s / E;
        const float* src = w + ((size_t)e * IN_DIM + kb * 32 + 2 * tq) * H_DIM + n0 + tn;
        r[0] = src[0];
        r[1] = src[H_DIM];
    };
    auto ld_X = [&](int kb, float4* xr) {
        const float* p0 = x + (size_t)row0 * IN_DIM + kb * 32 + kq * 8;
        const float* p1 = x + (size_t)row1 * IN_DIM + kb * 32 + kq * 8;
        xr[0] = *reinterpret_cast<const float4*>(p0);
        xr[1] = *reinterpret_cast<const float4*>(p0 + 4);
        xr[2] = *reinterpret_cast<const float4*>(p1);
        xr[3] = *reinterpret_cast<const float4*>(p1 + 4);
    };

    f32x4 acc0 = {0.f,0.f,0.f,0.f}, acc1 = {0.f,0.f,0.f,0.f};

    float wreg[2][2];                // 2-deep ring x k-pair
    float4 xreg[2][4];               // both kb's x, loaded up front
    ld_B(0, wreg[0]); ld_B(1, wreg[1]);
    ld_X(kb0, xreg[0]); ld_X(kb0 + 1, xreg[1]);

    #pragma unroll
    for (int s = 0; s < NS; ++s) {
        const int rs = s & 1, pb_ = s & 1, e = s % E, kbi = s / E;

        *reinterpret_cast<uint*>(&bs[pb_][lp][j0]) = pk2(wreg[rs][0], wreg[rs][1]);

        const float4* xc = xreg[kbi];
        U128 a0, a1;
        a0.us[0] = f2bf(xc[0].x * ce0[e]); a0.us[1] = f2bf(xc[0].y * ce0[e]);
        a0.us[2] = f2bf(xc[0].z * ce0[e]); a0.us[3] = f2bf(xc[0].w * ce0[e]);
        a0.us[4] = f2bf(xc[1].x * ce0[e]); a0.us[5] = f2bf(xc[1].y * ce0[e]);
        a0.us[6] = f2bf(xc[1].z * ce0[e]); a0.us[7] = f2bf(xc[1].w * ce0[e]);
        a1.us[0] = f2bf(xc[2].x * ce1[e]); a1.us[1] = f2bf(xc[2].y * ce1[e]);
        a1.us[2] = f2bf(xc[2].z * ce1[e]); a1.us[3] = f2bf(xc[2].w * ce1[e]);
        a1.us[4] = f2bf(xc[3].x * ce1[e]); a1.us[5] = f2bf(xc[3].y * ce1[e]);
        a1.us[6] = f2bf(xc[3].z * ce1[e]); a1.us[7] = f2bf(xc[3].w * ce1[e]);

        if (s + 2 < NS) ld_B(s + 2, wreg[rs]);   // ring refill (pre-barrier)

        __syncthreads();                         // staged tile visible
        U128 b0;
        b0.u4 = *reinterpret_cast<const uint4*>(&bs[pb_][l][0]);
        acc0 = __builtin_amdgcn_mfma_f32_16x16x32_bf16(a0.s8, b0.s8, acc0, 0, 0, 0);
        acc1 = __builtin_amdgcn_mfma_f32_16x16x32_bf16(a1.s8, b0.s8, acc1, 0, 0, 0);
    }

    const int colB = n0 + (l & 15);
    const int rsub = (l >> 4) << 2;
    #pragma unroll
    for (int mi = 0; mi < 2; ++mi) {
        const int row = wv * 32 + mi * 16 + rsub;
        const f32x4 c = mi ? acc1 : acc0;
        #pragma unroll
        for (int r = 0; r < 4; ++r)
            atomicAdd(&y1[(size_t)(row + r) * H_DIM + colB], c[r]);
    }
}

// ---------------------------------------------------------------------------
// gemm_mid: L2/L3, block tile 128 x 16, KPB=1 (6 steps), 17 splits (16 + z).
// Prologue: O(1) loads (elu(yin) or raw z). Same staging pipeline; epilogue
// atomicAdd into yout (bias pre-init; out itself for L3).
// ---------------------------------------------------------------------------
template<bool ZS, int NW, bool GUARD>
__device__ __forceinline__ void gemm_mid_body(
    const float* __restrict__ yin,   // [B][H_DIM] accum(+bias) pre-ELU
    const float* __restrict__ coef,  // [B][E]
    const float* __restrict__ z,     // [B][ZD]
    const float* __restrict__ w,     // [E][K2][NW]
    float* __restrict__ yout,        // [B][NW] accum (bias pre-init)
    int nt, int kb0, ushort (*bs)[64][8])
{
    constexpr int NS = E;            // 6 steps
    const int tid = threadIdx.x;
    const int l = tid & 63, wv = tid >> 6;
    const int n0 = nt * 16;
    const int tn = tid & 15, tq = tid >> 4;
    const int lp = ((tq >> 2) << 4) | tn;
    const int j0 = (2 * tq) & 7;
    const int row0 = 32 * wv + (l & 15), row1 = row0 + 16, kq = l >> 4;
    const bool okS = !GUARD || (n0 + tn) < NW;       // staging col valid
    const bool okC = !GUARD || (n0 + (l & 15)) < NW; // output col valid

    // ring loads first (independent of prologue chain)
    auto ld_B = [&](int s, float* r) {
        const float* src = w + ((size_t)s * K2 + kb0 * 32 + 2 * tq) * NW + n0 + tn;
        r[0] = okS ? src[0] : 0.f;
        r[1] = okS ? src[NW] : 0.f;
    };

    float wreg[2][2];
    ld_B(0, wreg[0]); ld_B(1, wreg[1]);

    float ce0[E], ce1[E];
    #pragma unroll
    for (int e = 0; e < E; ++e) {
        ce0[e] = coef[row0 * E + e];
        ce1[e] = coef[row1 * E + e];
    }

    // ---- prologue: per-thread activations for this k-range (8 values) ----
    float v0[8], v1[8];
    if (ZS) {
        const float4 za = *reinterpret_cast<const float4*>(z + row0 * ZD + kq * 8);
        const float4 zb = *reinterpret_cast<const float4*>(z + row0 * ZD + kq * 8 + 4);
        const float4 zc = *reinterpret_cast<const float4*>(z + row1 * ZD + kq * 8);
        const float4 zd = *reinterpret_cast<const float4*>(z + row1 * ZD + kq * 8 + 4);
        v0[0]=za.x; v0[1]=za.y; v0[2]=za.z; v0[3]=za.w;
        v0[4]=zb.x; v0[5]=zb.y; v0[6]=zb.z; v0[7]=zb.w;
        v1[0]=zc.x; v1[1]=zc.y; v1[2]=zc.z; v1[3]=zc.w;
        v1[4]=zd.x; v1[5]=zd.y; v1[6]=zd.z; v1[7]=zd.w;
    } else {
        const int kk = kb0 * 32 + kq * 8;
        const float* p0 = yin + (size_t)row0 * H_DIM + kk;
        const float* p1 = yin + (size_t)row1 * H_DIM + kk;
        const float4 a = *reinterpret_cast<const float4*>(p0);
        const float4 b = *reinterpret_cast<const float4*>(p0 + 4);
        const float4 c = *reinterpret_cast<const float4*>(p1);
        const float4 d = *reinterpret_cast<const float4*>(p1 + 4);
        v0[0]=elu1(a.x); v0[1]=elu1(a.y); v0[2]=elu1(a.z); v0[3]=elu1(a.w);
        v0[4]=elu1(b.x); v0[5]=elu1(b.y); v0[6]=elu1(b.z); v0[7]=elu1(b.w);
        v1[0]=elu1(c.x); v1[1]=elu1(c.y); v1[2]=elu1(c.z); v1[3]=elu1(c.w);
        v1[4]=elu1(d.x); v1[5]=elu1(d.y); v1[6]=elu1(d.z); v1[7]=elu1(d.w);
    }

    f32x4 acc0 = {0.f,0.f,0.f,0.f}, acc1 = {0.f,0.f,0.f,0.f};

    #pragma unroll
    for (int s = 0; s < NS; ++s) {
        const int rs = s & 1, pb_ = s & 1;

        *reinterpret_cast<uint*>(&bs[pb_][lp][j0]) = pk2(wreg[rs][0], wreg[rs][1]);

        U128 a0, a1;
        #pragma unroll
        for (int j = 0; j < 8; ++j) {
            a0.us[j] = f2bf(v0[j] * ce0[s]);
            a1.us[j] = f2bf(v1[j] * ce1[s]);
        }

        if (s + 2 < NS) ld_B(s + 2, wreg[rs]);

        __syncthreads();
        U128 b0;
        b0.u4 = *reinterpret_cast<const uint4*>(&bs[pb_][l][0]);
        acc0 = __builtin_amdgcn_mfma_f32_16x16x32_bf16(a0.s8, b0.s8, acc0, 0, 0, 0);
        acc1 = __builtin_amdgcn_mfma_f32_16x16x32_bf16(a1.s8, b0.s8, acc1, 0, 0, 0);
    }

    const int colB = n0 + (l & 15);
    const int rsub = (l >> 4) << 2;
    #pragma unroll
    for (int mi = 0; mi < 2; ++mi) {
        const int row = wv * 32 + mi * 16 + rsub;
        const f32x4 c = mi ? acc1 : acc0;
        #pragma unroll
        for (int r = 0; r < 4; ++r)
            if (okC) atomicAdd(&yout[(size_t)(row + r) * NW + colB], c[r]);
    }
}

__global__ __launch_bounds__(256) void gemm_l2(
    const float* __restrict__ y1, const float* __restrict__ coef,
    const float* __restrict__ z, const float* __restrict__ w2,
    float* __restrict__ y2)
{
    __shared__ ushort bs[2][64][8];
    const int nt = blockIdx.x, sp = blockIdx.y;
    if (sp < 16)
        gemm_mid_body<false, H_DIM, false>(y1, coef, z, w2, y2, nt, sp, bs);
    else
        gemm_mid_body<true, H_DIM, false>(y1, coef, z, w2, y2, nt, 16, bs);
}

__global__ __launch_bounds__(256) void gemm_l3(
    const float* __restrict__ y2, const float* __restrict__ coef,
    const float* __restrict__ z, const float* __restrict__ w3,
    float* __restrict__ out)
{
    __shared__ ushort bs[2][64][8];
    const int nt = blockIdx.x, sp = blockIdx.y;
    if (sp < 16)
        gemm_mid_body<false, OUT_DIM, true>(y2, coef, z, w3, out, nt, sp, bs);
    else
        gemm_mid_body<true, OUT_DIM, true>(y2, coef, z, w3, out, nt, 16, bs);
}

extern "C" void kernel_launch(void* const* d_in, const int* in_sizes, int n_in,
                              void* d_out, int out_size, void* d_ws, size_t ws_size,
                              hipStream_t stream)
{
    const float* p_prev = (const float*)d_in[0];
    const float* coef   = (const float*)d_in[1];
    const float* z      = (const float*)d_in[2];
    const float* w1     = (const float*)d_in[3];
    const float* b1     = (const float*)d_in[4];
    const float* w2     = (const float*)d_in[5];
    const float* b2     = (const float*)d_in[6];
    const float* w3     = (const float*)d_in[7];
    const float* b3     = (const float*)d_in[8];
    float* out = (float*)d_out;

    // ws: y1 | y2 (fp32 accumulators, re-initialized every call by init_bias)
    float* y1 = (float*)d_ws;            // [B][512]
    float* y2 = y1 + (size_t)B * H_DIM;  // [B][512]

    const int TOT = B * (2 * H_DIM + OUT_DIM);
    init_bias<<<(TOT + 255) / 256, 256, 0, stream>>>(coef, b1, b2, b3, y1, y2, out);
    gemm1<<<dim3(32, S1), 256, 0, stream>>>(p_prev, coef, w1, y1);
    gemm_l2<<<dim3(32, S23), 256, 0, stream>>>(y1, coef, z, w2, y2);
    gemm_l3<<<dim3(39, S23), 256, 0, stream>>>(y2, coef, z, w3, out);
}